// Round 5
// baseline (183.786 us; speedup 1.0000x reference)
//
#include <hip/hip_runtime.h>

// YOLO loss, MI355X. pred [256, 2704, 9, 5] fp32 (124.6 MB) -> scalar.
//
// Empirical record (total dur_us; ~130us is fixed fill+launch overhead):
//   R0 188.7/187.0 : 24336 blk, f4->VGPR->LDS staging, memset+3 kernels
//   R1 322.7 : 80B-stride regs (uncoalesced) + fence tail
//   R2 251.5 : grid-stride deep-serial (latency-bound) + fence tail
//   R3 479.9 : depth-4 regs, launch_bounds(256,8) serialized loads + fence tail
//   R4 182.9 : R0 structure, 512 elem/blk, rcp sigmoid, no fence, 3 dispatches  BEST
// This round (R5): keep R4 shape; only change kernel B staging:
//   - global_load_lds width=16 (HBM->LDS direct, no VGPR round-trip; the
//     m93->m97 lever). Our LDS layout is already linear in lane order, which
//     is exactly the HW's wave-uniform-base + lane*16 write pattern.
//   - 1024 elem/block: 5 direct loads/thread in flight, half the barriers
//     and atomics; 20KB LDS -> 8 blocks/CU -> still full 32-wave occupancy.
//
// ws layout (floats):
//  [0] coor_sq_obj  [1] conf_sq_obj  [2] coor_obj(label)  [3] conf_obj(iou)
//  [4 .. 4+256)        coor buckets (atomic)
//  [4+256 .. 4+512)    conf buckets (atomic)

#define GHW     52
#define GCELLS  2704          // 52*52
#define NA      9
#define BATCH   256
#define NBLK    (GCELLS * NA) // 24336 elements/sample; NBLK*BATCH = 6,230,016
#define INV52   (1.0f / 52.0f)
#define NBUCKET 256

#define ELEMS_B 1024                      // elements per block
#define NB2     6084                      // 6,230,016 / 1024 exactly
#define Q4_B    1280                      // float4s per block = 1024*5/4

typedef const __attribute__((address_space(1))) uint32_t glds_g;
typedef __attribute__((address_space(3))) uint32_t glds_l;

__device__ __forceinline__ float sigmoid_exact(float x) {
    return 1.0f / (1.0f + __expf(-x));    // IEEE div; only in tiny obj kernel
}

__device__ __forceinline__ float sigmoid_fast(float x) {
    return __builtin_amdgcn_rcpf(1.0f + __expf(-x));  // ~1 ulp; absmax 0.0 R1-R4
}

__device__ __forceinline__ float waveReduceSum(float v) {
#pragma unroll
    for (int o = 32; o > 0; o >>= 1) v += __shfl_down(v, o, 64);
    return v;
}

// ---------------- Kernel A: per-sample responsible box, IoU, obj sums -------
// Also zero-inits the bucket region (stream order makes it visible to B).
__global__ __launch_bounds__(256) void yolo_obj_kernel(
        const float* __restrict__ pred,
        const float* __restrict__ label,
        const float* __restrict__ anchors,
        float* __restrict__ ws) {
    __shared__ float anch[18];
    __shared__ float red[4][4];
    int b = threadIdx.x;

    ws[4 + b] = 0.0f;
    ws[4 + NBUCKET + b] = 0.0f;

    if (b < 18) anch[b] = anchors[b];
    __syncthreads();

    float4 lab = ((const float4*)label)[b];
    float lx = lab.x, ly = lab.y, lw = lab.z, lh = lab.w;

    int ix = (int)floorf(lx * 52.0f);
    int iy = (int)floorf(ly * 52.0f);
    int idx = ix * GHW + iy;

    // argmax over anchors of squared distance (first-max, strict >)
    int am = 0; float best = -1.0f;
#pragma unroll
    for (int a = 0; a < NA; ++a) {
        float dw = lw - anch[2 * a];
        float dh = lh - anch[2 * a + 1];
        float d = dw * dw + dh * dh;
        if (d > best) { best = d; am = a; }
    }

    const float* p = pred + (((size_t)b * GCELLS + idx) * NA + am) * 5;
    float v0 = p[0], v1 = p[1], v2 = p[2], v3 = p[3], v4 = p[4];

    float aw = anch[2 * am], ah = anch[2 * am + 1];
    float px = (sigmoid_exact(v0) + (float)ix) * INV52;
    float py = (sigmoid_exact(v1) + (float)iy) * INV52;
    float pw = aw * __expf(v2);
    float ph = ah * __expf(v3);
    float pc = sigmoid_exact(v4);

    float agx = ((float)ix + 0.5f) * INV52;
    float agy = ((float)iy + 0.5f) * INV52;

    float d0 = px - agx, d1 = py - agy, d2 = pw - aw, d3 = ph - ah;
    float coor_sq_obj = d0 * d0 + d1 * d1 + d2 * d2 + d3 * d3;
    float conf_sq_obj = pc * pc;

    float e0 = px - lx, e1 = py - ly, e2 = pw - lw, e3 = ph - lh;
    float coor_obj = e0 * e0 + e1 * e1 + e2 * e2 + e3 * e3;

    // IoU (faithful: areas = x2*y2, not (x2-x1)*(y2-y1))
    float lx1 = fmaxf(lx - lw * 0.5f, 0.0f), ly1 = fmaxf(ly - lh * 0.5f, 0.0f);
    float lx2 = fminf(lx + lw * 0.5f, 1.0f), ly2 = fminf(ly + lh * 0.5f, 1.0f);
    float qx1 = fmaxf(px - pw * 0.5f, 0.0f), qy1 = fmaxf(py - ph * 0.5f, 0.0f);
    float qx2 = fminf(px + pw * 0.5f, 1.0f), qy2 = fminf(py + ph * 0.5f, 1.0f);
    float ix1 = fmaxf(lx1, qx1), iy1 = fmaxf(ly1, qy1);
    float ix2 = fminf(lx2, qx2), iy2 = fminf(ly2, qy2);
    float la = lx2 * ly2, pa = qx2 * qy2;
    float inter = fmaxf(ix2 - ix1, 0.0f) * fmaxf(iy2 - iy1, 0.0f);
    float iou = inter / (la + pa - inter);
    float dcf = pc - iou;
    float conf_obj = dcf * dcf;

    float r0 = waveReduceSum(coor_sq_obj);
    float r1 = waveReduceSum(conf_sq_obj);
    float r2 = waveReduceSum(coor_obj);
    float r3 = waveReduceSum(conf_obj);
    int lane = threadIdx.x & 63, wid = threadIdx.x >> 6;
    if (lane == 0) {
        red[0][wid] = r0; red[1][wid] = r1; red[2][wid] = r2; red[3][wid] = r3;
    }
    __syncthreads();
    if (threadIdx.x < 4) {
        ws[threadIdx.x] = red[threadIdx.x][0] + red[threadIdx.x][1]
                        + red[threadIdx.x][2] + red[threadIdx.x][3];
    }
}

// ---------------- Kernel B: noobj reduction (124.6 MB pass) -----------------
// Block stages 1280 float4s (20KB) HBM->LDS direct via global_load_lds w=16:
// iteration i, wave w writes LDS float4s [i*256+w*64, +64) -- linear in lane
// order (HW pattern: wave-uniform base + lane*16), global source is per-lane
// coalesced. 5 loads in flight per thread, no VGPR round-trip. Threads then
// process 4 elements each from LDS (stride-5 reads: 2-way aliasing = free).
__global__ __launch_bounds__(256) void yolo_noobj_kernel(
        const float* __restrict__ pred,
        const float* __restrict__ anchors,
        float* __restrict__ ws) {
    __shared__ float4 sh4[Q4_B];        // 20KB
    __shared__ float anch[18];
    __shared__ float red[2][4];
    int t = threadIdx.x;

    const float4* __restrict__ g4 = (const float4*)pred;
    size_t f0 = (size_t)blockIdx.x * Q4_B;
    int wbase = t & ~63;                // wave*64, wave-uniform

#pragma unroll
    for (int i = 0; i < 5; ++i) {
        // per-lane global addr; wave-uniform LDS base (HW adds lane*16)
        __builtin_amdgcn_global_load_lds(
            (glds_g*)(g4 + f0 + i * 256 + t),
            (glds_l*)(sh4 + i * 256 + wbase),
            16, 0, 0);
    }
    if (t < 18) anch[t] = anchors[t];
    __syncthreads();                    // compiler emits vmcnt(0) drain here

    const float* sh = (const float*)sh4;
    float coorAcc = 0.0f, confAcc = 0.0f;
#pragma unroll
    for (int h = 0; h < 4; ++h) {
        int le = t + h * 256;                       // local element 0..1023
        int e  = blockIdx.x * ELEMS_B + le;         // global element < 6.23M
        int a  = e % NA;
        float aw = anch[2 * a], ah = anch[2 * a + 1];

        const float* m = sh + 5 * le;               // stride-5: 2-way (free)
        float v0 = m[0], v1 = m[1], v2 = m[2], v3 = m[3], v4 = m[4];

        float s0 = sigmoid_fast(v0);
        float s1 = sigmoid_fast(v1);
        float s4 = sigmoid_fast(v4);
        float t0 = (s0 - 0.5f) * INV52;             // == pred_x - anchors_grid_x
        float t1 = (s1 - 0.5f) * INV52;
        float t2 = aw * (__expf(v2) - 1.0f);        // == pred_w - anchor_w
        float t3 = ah * (__expf(v3) - 1.0f);

        coorAcc += t0 * t0 + t1 * t1 + t2 * t2 + t3 * t3;
        confAcc += s4 * s4;
    }

    float rc = waveReduceSum(coorAcc);
    float rf = waveReduceSum(confAcc);
    int lane = t & 63, wid = t >> 6;
    if (lane == 0) { red[0][wid] = rc; red[1][wid] = rf; }
    __syncthreads();
    if (t == 0) {
        float cs = red[0][0] + red[0][1] + red[0][2] + red[0][3];
        float fs = red[1][0] + red[1][1] + red[1][2] + red[1][3];
        int bk = blockIdx.x & (NBUCKET - 1);        // ~24 blocks/bucket
        atomicAdd(&ws[4 + bk], cs);
        atomicAdd(&ws[4 + NBUCKET + bk], fs);
    }
}

// ---------------- Kernel C: bucket reduce + final combine -------------------
__global__ __launch_bounds__(256) void yolo_fin_kernel(
        const float* __restrict__ ws,
        float* __restrict__ out) {
    __shared__ float red[2][4];
    int t = threadIdx.x;
    float c = ws[4 + t];
    float f = ws[4 + NBUCKET + t];
    float rc = waveReduceSum(c);
    float rf = waveReduceSum(f);
    int lane = t & 63, wid = t >> 6;
    if (lane == 0) { red[0][wid] = rc; red[1][wid] = rf; }
    __syncthreads();
    if (t == 0) {
        float coor_all = red[0][0] + red[0][1] + red[0][2] + red[0][3];
        float conf_all = red[1][0] + red[1][1] + red[1][2] + red[1][3];
        float coor_l_noobj = (coor_all - ws[0]) / (float)(BATCH * (NBLK - 1) * 4);
        float conf_l_noobj = (conf_all - ws[1]) / (float)(BATCH * (NBLK - 1));
        float coor_l_obj = ws[2] / (float)(BATCH * 4);
        float conf_l_obj = ws[3] / (float)BATCH;
        out[0] = coor_l_obj + coor_l_noobj + conf_l_obj + conf_l_noobj;
    }
}

extern "C" void kernel_launch(void* const* d_in, const int* in_sizes, int n_in,
                              void* d_out, int out_size, void* d_ws, size_t ws_size,
                              hipStream_t stream) {
    const float* pred    = (const float*)d_in[0];
    const float* label   = (const float*)d_in[1];
    const float* anchors = (const float*)d_in[2];
    float* out = (float*)d_out;
    float* ws  = (float*)d_ws;

    yolo_obj_kernel<<<1, 256, 0, stream>>>(pred, label, anchors, ws);
    yolo_noobj_kernel<<<NB2, 256, 0, stream>>>(pred, anchors, ws);
    yolo_fin_kernel<<<1, 256, 0, stream>>>(ws, out);
}